// Round 13
// baseline (131.518 us; speedup 1.0000x reference)
//
#include <hip/hip_runtime.h>
#include <hip/hip_bf16.h>

#define NROWS 8192
#define NC 256
#define KTOP 5
#define GAMMA 1.0f
#define MARGIN 2.0f
#define NSPLIT 32    // targ splits (256 rows each), 4 per XCD
#define PREDB 512    // pred rows per block (8 pg waves x 64 cols)
#define TCHUNK 32    // targ rows per LDS chunk
#define CHUNKS 8     // 256 / 32
#define NSLOT NSPLIT

typedef __bf16 bf16x8 __attribute__((ext_vector_type(8)));
typedef float f32x4 __attribute__((ext_vector_type(4)));
typedef _Float16 h2 __attribute__((ext_vector_type(2)));

// packed-f16 sorted-ascending top-5 insert (v_pk_max_f16 / v_pk_min_f16)
static __device__ __forceinline__ void ins5pk(h2 (&t)[KTOP], h2 v) {
    t[0] = __builtin_elementwise_max(t[0], __builtin_elementwise_min(v, t[1]));
    t[1] = __builtin_elementwise_max(t[1], __builtin_elementwise_min(v, t[2]));
    t[2] = __builtin_elementwise_max(t[2], __builtin_elementwise_min(v, t[3]));
    t[3] = __builtin_elementwise_max(t[3], __builtin_elementwise_min(v, t[4]));
    t[4] = __builtin_elementwise_max(t[4], v);
}

static __device__ __forceinline__ void ins5f(float (&t)[KTOP], float v) {
    t[0] = fmaxf(t[0], fminf(v, t[1]));
    t[1] = fmaxf(t[1], fminf(v, t[2]));
    t[2] = fmaxf(t[2], fminf(v, t[3]));
    t[3] = fmaxf(t[3], fminf(v, t[4]));
    t[4] = fmaxf(t[4], v);
}

// f32 pair -> packed f16 (v_cvt_pkrtz_f16_f32)
static __device__ __forceinline__ h2 pkrtz(float a, float b) {
    return __builtin_bit_cast(h2, __builtin_amdgcn_cvt_pkrtz(a, b));
}

// ---------------- Kernel A: row-normalize fp32 -> bf16 ----------------
__global__ __launch_bounds__(256) void norm_cast_kernel(
    const float* __restrict__ a, const float* __restrict__ b,
    unsigned short* __restrict__ an, unsigned short* __restrict__ bn) {
    const float* src = blockIdx.y ? b : a;
    unsigned short* dst = blockIdx.y ? bn : an;
    int row = blockIdx.x * 4 + (threadIdx.x >> 6);
    int lane = threadIdx.x & 63;
    float4 v = reinterpret_cast<const float4*>(src + (size_t)row * NC)[lane];
    float ss = v.x * v.x + v.y * v.y + v.z * v.z + v.w * v.w;
#pragma unroll
    for (int off = 32; off >= 1; off >>= 1) ss += __shfl_xor(ss, off);
    float inv = rsqrtf(ss);
    __hip_bfloat16 h0 = __float2bfloat16(v.x * inv);
    __hip_bfloat16 h1 = __float2bfloat16(v.y * inv);
    __hip_bfloat16 h2v = __float2bfloat16(v.z * inv);
    __hip_bfloat16 h3 = __float2bfloat16(v.w * inv);
    ushort4 o;
    o.x = __builtin_bit_cast(unsigned short, h0);
    o.y = __builtin_bit_cast(unsigned short, h1);
    o.z = __builtin_bit_cast(unsigned short, h2v);
    o.w = __builtin_bit_cast(unsigned short, h3);
    reinterpret_cast<ushort4*>(dst + (size_t)row * NC)[lane] = o;
}

// ------- Kernel B: fused sim GEMM + per-row running top-5 + diagonal -------
// grid = 512 (2/CU): 16 pred-blocks x 32 splits. Block = 512 thr = 8 waves,
// ALL pg (tg=1): each wave owns 64 pred cols, pb resident in 128 AGPRs
// ("+a" pin -> zero VGPR cost, MFMA reads B from AGPR). Targ streamed via
// 2x16KB LDS chunks; every wave reads the whole chunk (amp=8 but chunk is
// tiny): per-CU LDS reads = 128MB/64cols = 2MB (was 4MB at 32 cols).
__global__ __launch_bounds__(512) void simtop_kernel(
    const unsigned short* __restrict__ predn,
    const unsigned short* __restrict__ targn,
    float* __restrict__ diag, _Float16* __restrict__ top5p) {
    __shared__ unsigned short tb[2][TCHUNK][NC];  // 2 x 16 KB

    int tid = threadIdx.x, w = tid >> 6, lane = tid & 63;
    int l15 = lane & 15, lq = lane >> 4;
    int id = blockIdx.x;
    // (bi, split) decode: XCD x gets splits {4x..4x+3} (512KB targ in its L2)
    int xcd = id & 7, bi = (id >> 3) & 15, hi = id >> 7;
    int split = xcd * 4 + hi;
    int pgbase = bi * PREDB + w * 64;  // wave's 64 pred cols
    int ts0 = split * (CHUNKS * TCHUNK);

    // resident pred fragments: 4 col-groups x 8 kk = 128 regs, PINNED TO AGPR
    f32x4 pb0[8], pb1[8], pb2[8], pb3[8];
    {
        const unsigned short* pp = predn + (size_t)(pgbase + l15) * NC + lq * 8;
#pragma unroll
        for (int kk = 0; kk < 8; ++kk) {
            pb0[kk] = *reinterpret_cast<const f32x4*>(pp + kk * 32);
            pb1[kk] = *reinterpret_cast<const f32x4*>(pp + 16 * NC + kk * 32);
            pb2[kk] = *reinterpret_cast<const f32x4*>(pp + 32 * NC + kk * 32);
            pb3[kk] = *reinterpret_cast<const f32x4*>(pp + 48 * NC + kk * 32);
        }
    }
#pragma unroll
    for (int kk = 0; kk < 8; ++kk)
        asm volatile("" : "+a"(pb0[kk]), "+a"(pb1[kk]), "+a"(pb2[kk]),
                          "+a"(pb3[kk]));

    h2 t01[KTOP], t23[KTOP];
    h2 NEG = {(_Float16)-65504.f, (_Float16)-65504.f};
#pragma unroll
    for (int j = 0; j < KTOP; ++j) {
        t01[j] = NEG;
        t23[j] = NEG;
    }

    // diagonal: block sees it iff bi == split>>1; within, 32-col unit
    // u = (split&1)*8 + c belongs to wave u>>1, col-pair h = u&1
    bool dblk = (bi == (split >> 1));

    const char* tgbase = (const char*)(targn + (size_t)ts0 * NC);

    f32x4 sreg0, sreg1;  // 32B/thread staging
#define STAGE_LOAD(c)                                                       \
    {                                                                       \
        const char* src_ = tgbase + (size_t)(c) * (TCHUNK * NC * 2);        \
        sreg0 = *reinterpret_cast<const f32x4*>(src_ + tid * 16);           \
        sreg1 = *reinterpret_cast<const f32x4*>(src_ + 8192 + tid * 16);    \
    }
    // 16B-slot swizzle: slot' = slot ^ (row&7); ushort offset = slot'*8
#define STAGE_STORE(pb_)                                                    \
    {                                                                       \
        int L0_ = tid * 16, L1_ = 8192 + tid * 16;                          \
        int r0_ = L0_ >> 9, s0_ = (L0_ >> 4) & 31;                          \
        int r1_ = L1_ >> 9, s1_ = (L1_ >> 4) & 31;                          \
        *reinterpret_cast<f32x4*>(&tb[pb_][r0_][(s0_ ^ (r0_ & 7)) << 3]) =  \
            sreg0;                                                          \
        *reinterpret_cast<f32x4*>(&tb[pb_][r1_][(s1_ ^ (r1_ & 7)) << 3]) =  \
            sreg1;                                                          \
    }

    STAGE_LOAD(0);
    STAGE_STORE(0);
    __syncthreads();

    int r0 = l15, r1 = l15 + 16;  // wave's targ rows within chunk
    int sw0 = l15 & 7;            // same for r0 and r1

    for (int c = 0; c < CHUNKS; ++c) {
        int pbuf = c & 1;
        if (c + 1 < CHUNKS) STAGE_LOAD(c + 1);

        f32x4 z = {0.f, 0.f, 0.f, 0.f};
        f32x4 acc00 = z, acc01 = z, acc10 = z, acc11 = z;
        f32x4 acc20 = z, acc21 = z, acc30 = z, acc31 = z;  // [cg][rg]
        __builtin_amdgcn_s_setprio(1);
#pragma unroll
        for (int kk = 0; kk < 8; ++kk) {
            bf16x8 a0 = *reinterpret_cast<const bf16x8*>(
                &tb[pbuf][r0][(((kk << 2) + lq) ^ sw0) << 3]);
            bf16x8 a1 = *reinterpret_cast<const bf16x8*>(
                &tb[pbuf][r1][(((kk << 2) + lq) ^ sw0) << 3]);
            acc00 = __builtin_amdgcn_mfma_f32_16x16x32_bf16(
                a0, __builtin_bit_cast(bf16x8, pb0[kk]), acc00, 0, 0, 0);
            acc01 = __builtin_amdgcn_mfma_f32_16x16x32_bf16(
                a1, __builtin_bit_cast(bf16x8, pb0[kk]), acc01, 0, 0, 0);
            acc10 = __builtin_amdgcn_mfma_f32_16x16x32_bf16(
                a0, __builtin_bit_cast(bf16x8, pb1[kk]), acc10, 0, 0, 0);
            acc11 = __builtin_amdgcn_mfma_f32_16x16x32_bf16(
                a1, __builtin_bit_cast(bf16x8, pb1[kk]), acc11, 0, 0, 0);
            acc20 = __builtin_amdgcn_mfma_f32_16x16x32_bf16(
                a0, __builtin_bit_cast(bf16x8, pb2[kk]), acc20, 0, 0, 0);
            acc21 = __builtin_amdgcn_mfma_f32_16x16x32_bf16(
                a1, __builtin_bit_cast(bf16x8, pb2[kk]), acc21, 0, 0, 0);
            acc30 = __builtin_amdgcn_mfma_f32_16x16x32_bf16(
                a0, __builtin_bit_cast(bf16x8, pb3[kk]), acc30, 0, 0, 0);
            acc31 = __builtin_amdgcn_mfma_f32_16x16x32_bf16(
                a1, __builtin_bit_cast(bf16x8, pb3[kk]), acc31, 0, 0, 0);
        }
        __builtin_amdgcn_s_setprio(0);

        int u = ((split & 1) << 3) + c;
        if (__builtin_expect(dblk && (u >> 1) == w, 0)) {
            int h = u & 1;
#pragma unroll
            for (int j = 0; j < 4; ++j) {
                if (l15 == lq * 4 + j) {
                    if (h == 0) {
                        diag[pgbase + l15] = acc00[j];
                        acc00[j] = -65504.f;
                        diag[pgbase + 16 + l15] = acc11[j];
                        acc11[j] = -65504.f;
                    } else {
                        diag[pgbase + 32 + l15] = acc20[j];
                        acc20[j] = -65504.f;
                        diag[pgbase + 48 + l15] = acc31[j];
                        acc31[j] = -65504.f;
                    }
                }
            }
        }
#pragma unroll
        for (int j = 0; j < 4; ++j) {
            ins5pk(t01, pkrtz(acc00[j], acc10[j]));
            ins5pk(t01, pkrtz(acc01[j], acc11[j]));
            ins5pk(t23, pkrtz(acc20[j], acc30[j]));
            ins5pk(t23, pkrtz(acc21[j], acc31[j]));
        }

        if (c + 1 < CHUNKS) STAGE_STORE(pbuf ^ 1);
        __syncthreads();
    }

    // merge the 4 lq-lanes holding the same pred cols (butterfly ^16, ^32)
#pragma unroll
    for (int m = 16; m <= 32; m <<= 1) {
        h2 pv[KTOP], qv[KTOP];
#pragma unroll
        for (int j = 0; j < KTOP; ++j) {
            pv[j] = __builtin_bit_cast(
                h2, __shfl_xor(__builtin_bit_cast(int, t01[j]), m));
            qv[j] = __builtin_bit_cast(
                h2, __shfl_xor(__builtin_bit_cast(int, t23[j]), m));
        }
#pragma unroll
        for (int j = 0; j < KTOP; ++j) {
            ins5pk(t01, pv[j]);
            ins5pk(t23, qv[j]);
        }
    }

    if (lq == 0) {
        // one wave per (col, split): slot = split. f16 partials.
#pragma unroll
        for (int j = 0; j < KTOP; ++j) {
            _Float16* base = top5p + (size_t)(split * KTOP + j) * NROWS;
            base[pgbase + l15] = t01[j].x;
            base[pgbase + 16 + l15] = t01[j].y;
            base[pgbase + 32 + l15] = t23[j].x;
            base[pgbase + 48 + l15] = t23[j].y;
        }
    }
}

// ---------------- Kernel C: merge partials + loss reduction ----------------
__global__ __launch_bounds__(256) void finalize_kernel(
    const float* __restrict__ diag, const _Float16* __restrict__ top5p,
    float* __restrict__ out) {
    int row = blockIdx.x * 256 + threadIdx.x;
    float t5[KTOP];
#pragma unroll
    for (int j = 0; j < KTOP; ++j) t5[j] = -1e30f;
#pragma unroll 8
    for (int sj = 0; sj < NSLOT * KTOP; ++sj)
        ins5f(t5, (float)top5p[(size_t)sj * NROWS + row]);
    float d = diag[row];
    float sum = 0.f;
#pragma unroll
    for (int j = 0; j < KTOP; ++j)
        sum += fmaxf(t5[j] - GAMMA * d + MARGIN, 0.f);
#pragma unroll
    for (int off = 32; off >= 1; off >>= 1) sum += __shfl_xor(sum, off);
    __shared__ float red[4];
    int wv = threadIdx.x >> 6;
    if ((threadIdx.x & 63) == 0) red[wv] = sum;
    __syncthreads();
    if (threadIdx.x == 0) {
        float tot = red[0] + red[1] + red[2] + red[3];
        atomicAdd(out, tot * (1.0f / ((float)NROWS * KTOP)));
    }
}

extern "C" void kernel_launch(void* const* d_in, const int* in_sizes, int n_in,
                              void* d_out, int out_size, void* d_ws,
                              size_t ws_size, hipStream_t stream) {
    (void)in_sizes; (void)n_in; (void)out_size; (void)ws_size;
    const float* input = (const float*)d_in[0];
    const float* target = (const float*)d_in[1];
    char* ws = (char*)d_ws;
    unsigned short* predn = (unsigned short*)ws;                       // 4 MB
    unsigned short* targn = (unsigned short*)(ws + (size_t)NROWS * NC * 2);
    float* diag = (float*)(ws + (size_t)NROWS * NC * 4);               // 32 KB
    _Float16* top5p =
        (_Float16*)(ws + (size_t)NROWS * NC * 4 + NROWS * 4);          // 2.6 MB
    float* out = (float*)d_out;

    (void)hipMemsetAsync(d_out, 0, sizeof(float), stream);

    dim3 gA(NROWS / 4, 2);
    norm_cast_kernel<<<gA, 256, 0, stream>>>(input, target, predn, targn);

    simtop_kernel<<<512, 512, 0, stream>>>(predn, targn, diag, top5p);

    finalize_kernel<<<NROWS / 256, 256, 0, stream>>>(diag, top5p, out);
}